// Round 1
// baseline (35.574 us; speedup 1.0000x reference)
//
#include <hip/hip_runtime.h>
#include <cfloat>

// ChamferLossKL: bs=8, n=2048, d=4, fp32.
// 2*KL(pred_i || gt_j) = dot(pa_i, ivb_j) + dot(mua_i, m2_j) + ca_i + cb_j
//   pa = exp(lva) + mua^2, ca = -sum(lva) - d
//   ivb = exp(-lvb), m2 = -2*mub*ivb, cb = sum(mub^2*ivb) + sum(lvb)
// loss[b] = 0.5 * ( sum_i min_j s_ij + sum_j min_i s_ij )

#define NMAX 2048
#define ROWS 128
#define SEGS 8
#define TPB (ROWS * SEGS)  // 1024 threads, 16 waves

__global__ void precompute_kernel(
    const float4* __restrict__ mu_a, const float4* __restrict__ lv_a,
    const float4* __restrict__ mu_b, const float4* __restrict__ lv_b,
    float4* __restrict__ Av0, float4* __restrict__ Av1, float* __restrict__ Ac,
    float4* __restrict__ Bv0, float4* __restrict__ Bv1, float* __restrict__ Bc,
    int P)
{
    int i = blockIdx.x * blockDim.x + threadIdx.x;
    if (i >= P) return;

    // A-side (preds): row records for dir 0
    float4 mu = mu_a[i];
    float4 lv = lv_a[i];
    float4 ea = make_float4(__expf(lv.x), __expf(lv.y), __expf(lv.z), __expf(lv.w));
    float4 pa = make_float4(ea.x + mu.x * mu.x, ea.y + mu.y * mu.y,
                            ea.z + mu.z * mu.z, ea.w + mu.w * mu.w);
    Av0[i] = pa;
    Av1[i] = mu;
    Ac[i]  = -(lv.x + lv.y + lv.z + lv.w) - 4.0f;

    // B-side (gts)
    float4 mub = mu_b[i];
    float4 lvb = lv_b[i];
    float4 ivb = make_float4(__expf(-lvb.x), __expf(-lvb.y), __expf(-lvb.z), __expf(-lvb.w));
    float4 m2  = make_float4(-2.0f * mub.x * ivb.x, -2.0f * mub.y * ivb.y,
                             -2.0f * mub.z * ivb.z, -2.0f * mub.w * ivb.w);
    Bv0[i] = ivb;
    Bv1[i] = m2;
    Bc[i]  = mub.x * mub.x * ivb.x + mub.y * mub.y * ivb.y
           + mub.z * mub.z * ivb.z + mub.w * mub.w * ivb.w
           + (lvb.x + lvb.y + lvb.z + lvb.w);
}

__global__ __launch_bounds__(TPB) void chamfer_kl_kernel(
    const float4* __restrict__ Av0, const float4* __restrict__ Av1, const float* __restrict__ Ac,
    const float4* __restrict__ Bv0, const float4* __restrict__ Bv1, const float* __restrict__ Bc,
    float* __restrict__ out, int n)
{
    __shared__ float4 sv0[NMAX];        // 32 KB
    __shared__ float4 sv1[NMAX];        // 32 KB
    __shared__ float4 sc4[NMAX / 4];    // 8 KB
    __shared__ float  pmin[TPB];        // 4 KB
    __shared__ float  psum[2];

    const int t   = threadIdx.x;
    const int g   = blockIdx.x;   // row group
    const int b   = blockIdx.y;   // batch
    const int dir = blockIdx.z;   // 0: rows=preds(A), cols=gts(B); 1: rows=gts(B), cols=preds(A)

    const float4* cv0 = (dir ? Av0 : Bv0) + (size_t)b * n;
    const float4* cv1 = (dir ? Av1 : Bv1) + (size_t)b * n;
    const float*  cc  = (dir ? Ac  : Bc ) + (size_t)b * n;
    const float4* rv0 = (dir ? Bv0 : Av0) + (size_t)b * n;
    const float4* rv1 = (dir ? Bv1 : Av1) + (size_t)b * n;
    const float*  rc  = (dir ? Bc  : Ac ) + (size_t)b * n;

    // Stage column-side records into LDS (coalesced float4 copies)
    float* sc = (float*)sc4;
    for (int i = t; i < n; i += TPB) {
        sv0[i] = cv0[i];
        sv1[i] = cv1[i];
        sc[i]  = cc[i];
    }
    __syncthreads();

    const int row = t & (ROWS - 1);
    const int seg = t >> 7;           // 0..7
    const int r   = g * ROWS + row;

    const float4 r0 = rv0[r];
    const float4 r1 = rv1[r];
    const float  crow = rc[r];

    const int SEG = n / SEGS;         // 256
    const int j0  = seg * SEG;

    float smin = FLT_MAX;
    for (int jj = 0; jj < SEG; jj += 4) {
        float4 cb4 = sc4[(j0 + jj) >> 2];
#pragma unroll
        for (int u = 0; u < 4; ++u) {
            int j = j0 + jj + u;
            float4 v0 = sv0[j];
            float4 v1 = sv1[j];
            float cbu = (u == 0) ? cb4.x : (u == 1) ? cb4.y : (u == 2) ? cb4.z : cb4.w;
            float s = cbu;
            s = fmaf(r0.x, v0.x, s);
            s = fmaf(r0.y, v0.y, s);
            s = fmaf(r0.z, v0.z, s);
            s = fmaf(r0.w, v0.w, s);
            s = fmaf(r1.x, v1.x, s);
            s = fmaf(r1.y, v1.y, s);
            s = fmaf(r1.z, v1.z, s);
            s = fmaf(r1.w, v1.w, s);
            smin = fminf(smin, s);
        }
    }

    pmin[seg * ROWS + row] = smin;
    __syncthreads();

    if (t < ROWS) {
        float m = pmin[t];
#pragma unroll
        for (int s2 = 1; s2 < SEGS; ++s2) m = fminf(m, pmin[s2 * ROWS + t]);
        m += crow;  // per-row constant, excluded from inner loop (min-invariant)
        // 64-lane wave reduction (two waves: t in [0,64) and [64,128))
        for (int off = 32; off > 0; off >>= 1)
            m += __shfl_down(m, off, 64);
        if ((t & 63) == 0) psum[t >> 6] = m;
    }
    __syncthreads();

    if (t == 0) {
        atomicAdd(&out[b], 0.5f * (psum[0] + psum[1]));
    }
}

extern "C" void kernel_launch(void* const* d_in, const int* in_sizes, int n_in,
                              void* d_out, int out_size, void* d_ws, size_t ws_size,
                              hipStream_t stream) {
    const float4* mu_a = (const float4*)d_in[0];  // mu_preds
    const float4* lv_a = (const float4*)d_in[1];  // logvar_preds
    const float4* mu_b = (const float4*)d_in[2];  // mu_gts
    const float4* lv_b = (const float4*)d_in[3];  // logvar_gts

    const int bs = out_size;              // 8
    const int P  = in_sizes[0] / 4;       // total points (d=4), 16384
    const int n  = P / bs;                // 2048

    float* ws = (float*)d_ws;
    float4* Av0 = (float4*)(ws);
    float4* Av1 = (float4*)(ws + 4 * (size_t)P);
    float*  Ac  = ws + 8 * (size_t)P;
    float4* Bv0 = (float4*)(ws + 9 * (size_t)P);
    float4* Bv1 = (float4*)(ws + 13 * (size_t)P);
    float*  Bc  = ws + 17 * (size_t)P;

    hipMemsetAsync(d_out, 0, bs * sizeof(float), stream);

    precompute_kernel<<<(P + 255) / 256, 256, 0, stream>>>(
        mu_a, lv_a, mu_b, lv_b, Av0, Av1, Ac, Bv0, Bv1, Bc, P);

    dim3 grid(n / ROWS, bs, 2);
    chamfer_kl_kernel<<<grid, TPB, 0, stream>>>(Av0, Av1, Ac, Bv0, Bv1, Bc,
                                                (float*)d_out, n);
}

// Round 2
// 30.206 us; speedup vs baseline: 1.1777x; 1.1777x over previous
//
#include <hip/hip_runtime.h>
#include <cfloat>

// ChamferLossKL: bs=8, n=2048, d=4, fp32.
// 2*KL(pred_i || gt_j) = dot(pa_i, ivb_j) + dot(mua_i, m2_j) + ca_i + cb_j
//   A-record (first arg of KL):  pa = exp(lva)+mua^2, v1 = mua, c = -sum(lva)-d
//   B-record (second arg of KL): ivb = exp(-lvb), m2 = -2*mub*ivb,
//                                c = sum(mub^2*ivb) + sum(lvb)
// loss[b] = 0.5 * ( sum_rows_dir0 min_col s  +  sum_rows_dir1 min_col s )
//
// Fused single kernel: each block stages 2048 column records in LDS (computed
// from raw inputs), each thread register-tiles 8 rows so every LDS column
// read is reused 8x (prev round was LDS-return-BW bound at 1 row/thread).

#define TPB   1024
#define RPT   8                 // rows per thread (register-tiled)
#define WAVES (TPB / 64)        // 16
#define ROWSPB (WAVES * RPT)    // 128 rows per block

__global__ __launch_bounds__(TPB) void chamfer_kl_fused(
    const float4* __restrict__ mu_a, const float4* __restrict__ lv_a,
    const float4* __restrict__ mu_b, const float4* __restrict__ lv_b,
    float* __restrict__ out, int n)
{
    __shared__ float4 sv0[2048];   // 32 KB
    __shared__ float4 sv1[2048];   // 32 KB
    __shared__ float  sc[2048];    // 8 KB
    __shared__ float  psum[WAVES];

    const int t    = threadIdx.x;
    const int g    = blockIdx.x;   // row group
    const int b    = blockIdx.y;   // batch
    const int dir  = blockIdx.z;   // 0: rows=preds(A-type), cols=gts(B-type); 1: swapped
    const int lane = t & 63;
    const int wid  = t >> 6;

    const float4* cmu = (dir ? mu_a : mu_b) + (size_t)b * n;
    const float4* clv = (dir ? lv_a : lv_b) + (size_t)b * n;
    const float4* rmu = (dir ? mu_b : mu_a) + (size_t)b * n;
    const float4* rlv = (dir ? lv_b : lv_a) + (size_t)b * n;

    // ---- stage column records into LDS (dir==0 -> B-type, dir==1 -> A-type)
    for (int i = t; i < n; i += TPB) {
        float4 mu = cmu[i];
        float4 lv = clv[i];
        if (dir == 0) {
            float4 iv = make_float4(__expf(-lv.x), __expf(-lv.y),
                                    __expf(-lv.z), __expf(-lv.w));
            sv0[i] = iv;
            sv1[i] = make_float4(-2.0f * mu.x * iv.x, -2.0f * mu.y * iv.y,
                                 -2.0f * mu.z * iv.z, -2.0f * mu.w * iv.w);
            sc[i]  = mu.x * mu.x * iv.x + mu.y * mu.y * iv.y
                   + mu.z * mu.z * iv.z + mu.w * mu.w * iv.w
                   + (lv.x + lv.y + lv.z + lv.w);
        } else {
            float4 e = make_float4(__expf(lv.x), __expf(lv.y),
                                   __expf(lv.z), __expf(lv.w));
            sv0[i] = make_float4(e.x + mu.x * mu.x, e.y + mu.y * mu.y,
                                 e.z + mu.z * mu.z, e.w + mu.w * mu.w);
            sv1[i] = mu;
            sc[i]  = -(lv.x + lv.y + lv.z + lv.w) - 4.0f;
        }
    }

    // ---- row records in registers (dir==0 -> A-type, dir==1 -> B-type)
    float4 r0[RPT], r1[RPT];
    float  rcst[RPT];
    const int rbase = g * ROWSPB + wid * RPT;
#pragma unroll
    for (int r = 0; r < RPT; ++r) {
        float4 mu = rmu[rbase + r];
        float4 lv = rlv[rbase + r];
        if (dir == 0) {
            float4 e = make_float4(__expf(lv.x), __expf(lv.y),
                                   __expf(lv.z), __expf(lv.w));
            r0[r] = make_float4(e.x + mu.x * mu.x, e.y + mu.y * mu.y,
                                e.z + mu.z * mu.z, e.w + mu.w * mu.w);
            r1[r] = mu;
            rcst[r] = -(lv.x + lv.y + lv.z + lv.w) - 4.0f;
        } else {
            float4 iv = make_float4(__expf(-lv.x), __expf(-lv.y),
                                    __expf(-lv.z), __expf(-lv.w));
            r0[r] = iv;
            r1[r] = make_float4(-2.0f * mu.x * iv.x, -2.0f * mu.y * iv.y,
                                -2.0f * mu.z * iv.z, -2.0f * mu.w * iv.w);
            rcst[r] = mu.x * mu.x * iv.x + mu.y * mu.y * iv.y
                    + mu.z * mu.z * iv.z + mu.w * mu.w * iv.w
                    + (lv.x + lv.y + lv.z + lv.w);
        }
    }
    __syncthreads();

    // ---- main sweep: each wave scans all n columns for its 8 rows.
    // lane <-> column mapping j = jj*64 + lane: consecutive 16B LDS reads,
    // conflict-free; column record reused 8x from registers.
    float smin[RPT];
#pragma unroll
    for (int r = 0; r < RPT; ++r) smin[r] = FLT_MAX;

    const int NJ = n >> 6;   // 32
    for (int jj = 0; jj < NJ; ++jj) {
        const int j = (jj << 6) + lane;
        const float4 c0 = sv0[j];
        const float4 c1 = sv1[j];
        const float  cb = sc[j];
#pragma unroll
        for (int r = 0; r < RPT; ++r) {
            float s = cb;
            s = fmaf(r0[r].x, c0.x, s);
            s = fmaf(r0[r].y, c0.y, s);
            s = fmaf(r0[r].z, c0.z, s);
            s = fmaf(r0[r].w, c0.w, s);
            s = fmaf(r1[r].x, c1.x, s);
            s = fmaf(r1[r].y, c1.y, s);
            s = fmaf(r1[r].z, c1.z, s);
            s = fmaf(r1[r].w, c1.w, s);
            smin[r] = fminf(smin[r], s);
        }
    }

    // ---- per-row min across the 64 lanes (butterfly), then per-wave sum
    float local = 0.0f;
#pragma unroll
    for (int r = 0; r < RPT; ++r) {
        float m = smin[r];
#pragma unroll
        for (int off = 32; off; off >>= 1)
            m = fminf(m, __shfl_xor(m, off, 64));
        local += m + rcst[r];
    }
    if (lane == 0) psum[wid] = local;
    __syncthreads();

    if (t == 0) {
        float s = 0.0f;
#pragma unroll
        for (int w = 0; w < WAVES; ++w) s += psum[w];
        atomicAdd(&out[b], 0.5f * s);
    }
}

extern "C" void kernel_launch(void* const* d_in, const int* in_sizes, int n_in,
                              void* d_out, int out_size, void* d_ws, size_t ws_size,
                              hipStream_t stream) {
    const float4* mu_a = (const float4*)d_in[0];  // mu_preds
    const float4* lv_a = (const float4*)d_in[1];  // logvar_preds
    const float4* mu_b = (const float4*)d_in[2];  // mu_gts
    const float4* lv_b = (const float4*)d_in[3];  // logvar_gts

    const int bs = out_size;              // 8
    const int P  = in_sizes[0] / 4;       // 16384 points (d=4)
    const int n  = P / bs;                // 2048

    hipMemsetAsync(d_out, 0, bs * sizeof(float), stream);

    dim3 grid(n / ROWSPB, bs, 2);         // (16, 8, 2) = 256 blocks, 1/CU
    chamfer_kl_fused<<<grid, TPB, 0, stream>>>(mu_a, lv_a, mu_b, lv_b,
                                               (float*)d_out, n);
}

// Round 3
// 24.958 us; speedup vs baseline: 1.4253x; 1.2102x over previous
//
#include <hip/hip_runtime.h>
#include <cfloat>

// ChamferLossKL: bs=8, n=2048, d=4, fp32.
// 2*KL(pred_i || gt_j) = dot(pa_i, ivb_j) + dot(mua_i, m2_j) + ca_i + cb_j
//   A-record (first arg of KL):  pa = exp(lva)+mua^2, v1 = mua, c = -sum(lva)-d
//   B-record (second arg of KL): ivb = exp(-lvb), m2 = -2*mub*ivb,
//                                c = sum(mub^2*ivb) + sum(lvb)
// loss[b] = 0.5 * ( sum_rows_dir0 min_col s  +  sum_rows_dir1 min_col s )
//
// R2->R3: the hipMemsetAsync(d_out) mapped to a ~40us fillBufferAligned
// dispatch inside the graph (rocprof: WRITE_SIZE=0.031KB, dur 40us). Replaced
// atomic accumulation with per-block partials in d_ws + a tiny reduce kernel
// that overwrites out[] directly (no zero-init, poison-safe).

#define TPB   1024
#define RPT   8                 // rows per thread (register-tiled)
#define WAVES (TPB / 64)        // 16
#define ROWSPB (WAVES * RPT)    // 128 rows per block

__global__ __launch_bounds__(TPB) void chamfer_kl_fused(
    const float4* __restrict__ mu_a, const float4* __restrict__ lv_a,
    const float4* __restrict__ mu_b, const float4* __restrict__ lv_b,
    float* __restrict__ part, int n)
{
    __shared__ float4 sv0[2048];   // 32 KB
    __shared__ float4 sv1[2048];   // 32 KB
    __shared__ float  sc[2048];    // 8 KB
    __shared__ float  psum[WAVES];

    const int t    = threadIdx.x;
    const int g    = blockIdx.x;   // row group (16)
    const int b    = blockIdx.y;   // batch (8)
    const int dir  = blockIdx.z;   // 0: rows=preds(A-type), cols=gts(B-type); 1: swapped
    const int lane = t & 63;
    const int wid  = t >> 6;

    const float4* cmu = (dir ? mu_a : mu_b) + (size_t)b * n;
    const float4* clv = (dir ? lv_a : lv_b) + (size_t)b * n;
    const float4* rmu = (dir ? mu_b : mu_a) + (size_t)b * n;
    const float4* rlv = (dir ? lv_b : lv_a) + (size_t)b * n;

    // ---- stage column records into LDS (dir==0 -> B-type, dir==1 -> A-type)
    for (int i = t; i < n; i += TPB) {
        float4 mu = cmu[i];
        float4 lv = clv[i];
        if (dir == 0) {
            float4 iv = make_float4(__expf(-lv.x), __expf(-lv.y),
                                    __expf(-lv.z), __expf(-lv.w));
            sv0[i] = iv;
            sv1[i] = make_float4(-2.0f * mu.x * iv.x, -2.0f * mu.y * iv.y,
                                 -2.0f * mu.z * iv.z, -2.0f * mu.w * iv.w);
            sc[i]  = mu.x * mu.x * iv.x + mu.y * mu.y * iv.y
                   + mu.z * mu.z * iv.z + mu.w * mu.w * iv.w
                   + (lv.x + lv.y + lv.z + lv.w);
        } else {
            float4 e = make_float4(__expf(lv.x), __expf(lv.y),
                                   __expf(lv.z), __expf(lv.w));
            sv0[i] = make_float4(e.x + mu.x * mu.x, e.y + mu.y * mu.y,
                                 e.z + mu.z * mu.z, e.w + mu.w * mu.w);
            sv1[i] = mu;
            sc[i]  = -(lv.x + lv.y + lv.z + lv.w) - 4.0f;
        }
    }

    // ---- row records in registers (dir==0 -> A-type, dir==1 -> B-type)
    float4 r0[RPT], r1[RPT];
    float  rcst[RPT];
    const int rbase = g * ROWSPB + wid * RPT;
#pragma unroll
    for (int r = 0; r < RPT; ++r) {
        float4 mu = rmu[rbase + r];
        float4 lv = rlv[rbase + r];
        if (dir == 0) {
            float4 e = make_float4(__expf(lv.x), __expf(lv.y),
                                   __expf(lv.z), __expf(lv.w));
            r0[r] = make_float4(e.x + mu.x * mu.x, e.y + mu.y * mu.y,
                                e.z + mu.z * mu.z, e.w + mu.w * mu.w);
            r1[r] = mu;
            rcst[r] = -(lv.x + lv.y + lv.z + lv.w) - 4.0f;
        } else {
            float4 iv = make_float4(__expf(-lv.x), __expf(-lv.y),
                                    __expf(-lv.z), __expf(-lv.w));
            r0[r] = iv;
            r1[r] = make_float4(-2.0f * mu.x * iv.x, -2.0f * mu.y * iv.y,
                                -2.0f * mu.z * iv.z, -2.0f * mu.w * iv.w);
            rcst[r] = mu.x * mu.x * iv.x + mu.y * mu.y * iv.y
                    + mu.z * mu.z * iv.z + mu.w * mu.w * iv.w
                    + (lv.x + lv.y + lv.z + lv.w);
        }
    }
    __syncthreads();

    // ---- main sweep: each wave scans all n columns for its 8 rows.
    // lane <-> column mapping j = jj*64 + lane: consecutive 16B LDS reads,
    // conflict-free; column record reused 8x from registers.
    float smin[RPT];
#pragma unroll
    for (int r = 0; r < RPT; ++r) smin[r] = FLT_MAX;

    const int NJ = n >> 6;   // 32
    for (int jj = 0; jj < NJ; ++jj) {
        const int j = (jj << 6) + lane;
        const float4 c0 = sv0[j];
        const float4 c1 = sv1[j];
        const float  cb = sc[j];
#pragma unroll
        for (int r = 0; r < RPT; ++r) {
            float s = cb;
            s = fmaf(r0[r].x, c0.x, s);
            s = fmaf(r0[r].y, c0.y, s);
            s = fmaf(r0[r].z, c0.z, s);
            s = fmaf(r0[r].w, c0.w, s);
            s = fmaf(r1[r].x, c1.x, s);
            s = fmaf(r1[r].y, c1.y, s);
            s = fmaf(r1[r].z, c1.z, s);
            s = fmaf(r1[r].w, c1.w, s);
            smin[r] = fminf(smin[r], s);
        }
    }

    // ---- per-row min across the 64 lanes (butterfly), then per-wave sum
    float local = 0.0f;
#pragma unroll
    for (int r = 0; r < RPT; ++r) {
        float m = smin[r];
#pragma unroll
        for (int off = 32; off; off >>= 1)
            m = fminf(m, __shfl_xor(m, off, 64));
        local += m + rcst[r];
    }
    if (lane == 0) psum[wid] = local;
    __syncthreads();

    if (t == 0) {
        float s = 0.0f;
#pragma unroll
        for (int w = 0; w < WAVES; ++w) s += psum[w];
        part[b * 32 + dir * 16 + g] = 0.5f * s;   // plain store, no atomics
    }
}

// 1 block, 256 threads: wave w handles batches 2w and 2w+1 (32 partials each).
__global__ __launch_bounds__(256) void reduce_kernel(
    const float* __restrict__ part, float* __restrict__ out)
{
    const int t = threadIdx.x;
    const int w = t >> 6, lane = t & 63;
    const int b = 2 * w + (lane >> 5);
    float v = part[b * 32 + (lane & 31)];
#pragma unroll
    for (int off = 16; off; off >>= 1)
        v += __shfl_xor(v, off, 64);   // reduces within each 32-lane half
    if ((lane & 31) == 0) out[b] = v;  // overwrites poison; no zero-init needed
}

extern "C" void kernel_launch(void* const* d_in, const int* in_sizes, int n_in,
                              void* d_out, int out_size, void* d_ws, size_t ws_size,
                              hipStream_t stream) {
    const float4* mu_a = (const float4*)d_in[0];  // mu_preds
    const float4* lv_a = (const float4*)d_in[1];  // logvar_preds
    const float4* mu_b = (const float4*)d_in[2];  // mu_gts
    const float4* lv_b = (const float4*)d_in[3];  // logvar_gts

    const int bs = out_size;              // 8
    const int P  = in_sizes[0] / 4;       // 16384 points (d=4)
    const int n  = P / bs;                // 2048

    float* part = (float*)d_ws;           // 256 floats

    dim3 grid(n / ROWSPB, bs, 2);         // (16, 8, 2) = 256 blocks, 1/CU
    chamfer_kl_fused<<<grid, TPB, 0, stream>>>(mu_a, lv_a, mu_b, lv_b, part, n);
    reduce_kernel<<<1, 256, 0, stream>>>(part, (float*)d_out);
}